// Round 14
// baseline (2375.561 us; speedup 1.0000x reference)
//
#include <hip/hip_runtime.h>

// File-scope: forbid implicit fma contraction (keeps every a*b+c as two
// single-rounded IEEE ops, matching the numpy reference bit-for-bit).
#pragma clang fp contract(off)

#define NPOINT 2048
#define NSAMPLE 32
#define NPTS 8192
#define NB 4
#define CH 16
#define FPS_THREADS 256
#define PTS_PER_THREAD (NPTS / FPS_THREADS) /* 32 */
#define PAIRS (PTS_PER_THREAD / 2)          /* 16 */
#define FPS_WAVES (FPS_THREADS / 64)        /* 4 */

typedef unsigned long long u64;
typedef float v2f __attribute__((ext_vector_type(2)));

// Output layout (flat float32, concatenated in reference return order)
#define OFF_NEWXYZ 0
#define OFF_NEWPTS (NB * NPOINT * 3)                          /* 24576 */
#define OFF_IDX (OFF_NEWPTS + NB * NPOINT * NSAMPLE * CH)     /* 4218880 */
#define OFF_GXYZ (OFF_IDX + NB * NPOINT * NSAMPLE)            /* 4481024 */

template <int CTRL>
__device__ __forceinline__ float dpp_fmax(float v) {
  // bound_ctrl=true -> 0-fill; distances are >= 0 so 0 is a safe identity.
  int o = __builtin_amdgcn_update_dpp(0, __float_as_int(v), CTRL, 0xf, 0xf, true);
  return fmaxf(v, __int_as_float(o));
}

// ---------------- FPS: one block per batch, sequential 2048-step scan ------
// Reference semantics: idxs[0]=0; each step: dists=min(dists,|p-p_last|^2),
// next = argmax(dists) with FIRST-index tie-break. Op order mirrored:
// (dx*dx + dy*dy) + dz*dz, single-rounded IEEE, no fma contraction.
//
// R13 post-mortem: wall/iter ~2100 cyc across ALL wave configs -> a serial
// chain floor: barrier -> kslot read -> lpxyz read -> distance -> DPP ->
// ballot/readlane -> LDS atomic (drain) -> barrier. R14 cuts chain links:
//  - no atomic: each wave's winner lane ds_write_b64's its key to
//    slots[parity][wave]; next iter all threads read 4 keys (2 broadcast
//    ds_read_b128) and 3-compare u64 max locally. Parity double-buffer
//    keeps one barrier/iter, both directions barrier-separated.
//  - v2f packed distance loop (16 pairs), value-only max in-loop; index
//    recovered post-loop by a descending scan on ONE lane per wave.
// Key = (distbits<<32)|(8191-idx): u64 max => max dist, tie => lowest index
// (exact jnp.argmax tie-break). Contiguous ownership (thread t owns points
// t*32..t*32+31) keeps (wave,lane,j) order == global index order.
__global__ __launch_bounds__(FPS_THREADS)
__attribute__((amdgpu_waves_per_eu(1))) void fps_kernel(
    const float* __restrict__ in, float* __restrict__ out) {
  __shared__ float4 lpxyz[NPTS];      // 128 KB; winner coords: 1 ds_read_b128
  __shared__ float newb[NPOINT * 3];  // 24 KB newxyz staging
  __shared__ alignas(16) u64 slots[2][FPS_WAVES];  // per-wave argmax keys

  const int b = blockIdx.x;
  const int tid = threadIdx.x;
  const int lane = tid & 63;
  const int wv = tid >> 6;
  const float* base = in + (size_t)b * NPTS * CH;

  v2f pxv[PAIRS], pyv[PAIRS], pzv[PAIRS], dv[PAIRS];
#pragma unroll
  for (int jp = 0; jp < PAIRS; ++jp) {
    int p0 = tid * PTS_PER_THREAD + 2 * jp;
    float4 r0 = *reinterpret_cast<const float4*>(base + (size_t)p0 * CH);
    float4 r1 = *reinterpret_cast<const float4*>(base + (size_t)(p0 + 1) * CH);
    pxv[jp] = (v2f){r0.x, r1.x};
    pyv[jp] = (v2f){r0.y, r1.y};
    pzv[jp] = (v2f){r0.z, r1.z};
    lpxyz[p0] = r0;
    lpxyz[p0 + 1] = r1;
    dv[jp] = (v2f){__builtin_inff(), __builtin_inff()};
  }
  // Prime parity-0 slots: slot 0 = (+inf, idx 0) wins the first compare.
  if (tid < FPS_WAVES)
    slots[0][tid] = (tid == 0) ? (((u64)0x7f800000u << 32) | 8191u) : 0ull;

  for (int it = 0; it < NPOINT; ++it) {
    __syncthreads();  // separates slot writes (it-1) from reads (it)
    // Read all 4 wave keys (broadcast, 2x ds_read_b128), 3-compare u64 max.
    const ulonglong2 s01 =
        *reinterpret_cast<const ulonglong2*>(&slots[it & 1][0]);
    const ulonglong2 s23 =
        *reinterpret_cast<const ulonglong2*>(&slots[it & 1][2]);
    u64 k = s01.x;
    k = (s01.y > k) ? s01.y : k;
    k = (s23.x > k) ? s23.x : k;
    k = (s23.y > k) ? s23.y : k;
    const int gi = 8191 - (int)(unsigned)k;  // low 32 bits = 8191-idx
    // Winner coords: broadcast LDS read.
    const float4 g = lpxyz[gi];
    const float gx = g.x, gy = g.y, gz = g.z;
    if (tid == 0) {
      newb[it * 3 + 0] = gx;
      newb[it * 3 + 1] = gy;
      newb[it * 3 + 2] = gz;
    }
    // Distance update (packed pairs; exact IEEE per-element) + value max.
    float bestv = -1.0f;
#pragma unroll
    for (int jp = 0; jp < PAIRS; ++jp) {
      v2f dx = pxv[jp] - gx;
      v2f dy = pyv[jp] - gy;
      v2f dz = pzv[jp] - gz;
      v2f nd = (dx * dx + dy * dy) + dz * dz;
      v2f dn = {fminf(dv[jp].x, nd.x), fminf(dv[jp].y, nd.y)};
      dv[jp] = dn;
      bestv = fmaxf(bestv, fmaxf(dn.x, dn.y));
    }
    // Wave max via 6 DPP rounds -> lane 63; ballot -> lowest matching lane.
    float wm = bestv;
    wm = dpp_fmax<0x111>(wm);  // row_shr:1
    wm = dpp_fmax<0x112>(wm);  // row_shr:2
    wm = dpp_fmax<0x114>(wm);  // row_shr:4
    wm = dpp_fmax<0x118>(wm);  // row_shr:8
    wm = dpp_fmax<0x142>(wm);  // row_bcast15
    wm = dpp_fmax<0x143>(wm);  // row_bcast31
    const float swm =
        __int_as_float(__builtin_amdgcn_readlane(__float_as_int(wm), 63));
    const u64 wbal = __ballot(bestv == swm);
    const int wl = (int)__builtin_ctzll(wbal);
    if (lane == wl) {
      // Winner lane recovers its lowest matching j (descending scan) and
      // writes its own key — no readlane round-trip needed.
      const float* df = (const float*)dv;
      int bestj = 0;
#pragma unroll
      for (int jj = PTS_PER_THREAD - 1; jj >= 0; --jj)
        if (df[jj] == bestv) bestj = jj;
      const unsigned besti = (unsigned)(tid * PTS_PER_THREAD + bestj);
      slots[(it + 1) & 1][wv] =
          ((u64)__float_as_uint(bestv) << 32) | (8191u - besti);
    }
  }
  __syncthreads();
  // Dump staged newxyz to global once.
  float* ob = out + OFF_NEWXYZ + (size_t)b * NPOINT * 3;
  for (int i = tid; i < NPOINT * 3; i += FPS_THREADS) ob[i] = newb[i];
}

// ---------------- Ball query + group: one wave per query -------------------
__device__ __forceinline__ void write_slot(float* __restrict__ out,
                                           const float* __restrict__ base,
                                           int b, int qi, int s, int p,
                                           float4 r0, float qx, float qy,
                                           float qz) {
  float dx = __fsub_rn(r0.x, qx);
  float dy = __fsub_rn(r0.y, qy);
  float dz = __fsub_rn(r0.z, qz);
  size_t qs = (size_t)b * NPOINT + qi;
  out[OFF_IDX + qs * NSAMPLE + s] = (float)p;  // idx stored as float32
  float* g = out + OFF_GXYZ + (qs * NSAMPLE + s) * 3;
  g[0] = dx;
  g[1] = dy;
  g[2] = dz;
  const float* row = base + (size_t)p * CH;
  float4 r1 = *reinterpret_cast<const float4*>(row + 4);
  float4 r2 = *reinterpret_cast<const float4*>(row + 8);
  float4 r3 = *reinterpret_cast<const float4*>(row + 12);
  float* np_ = out + OFF_NEWPTS + (qs * NSAMPLE + s) * CH;
  *reinterpret_cast<float4*>(np_ + 0) = make_float4(dx, dy, dz, r0.w);
  *reinterpret_cast<float4*>(np_ + 4) = r1;
  *reinterpret_cast<float4*>(np_ + 8) = r2;
  *reinterpret_cast<float4*>(np_ + 12) = r3;
}

__global__ __launch_bounds__(256) void ballq_kernel(
    const float* __restrict__ in, float* __restrict__ out) {
  const int lane = threadIdx.x & 63;
  const int qid = blockIdx.x * 4 + (threadIdx.x >> 6);
  const int b = qid >> 11;    // / NPOINT
  const int qi = qid & 2047;  // % NPOINT
  const float* base = in + (size_t)b * NPTS * CH;
  const float* q = out + OFF_NEWXYZ + ((size_t)b * NPOINT + qi) * 3;
  float qx = q[0], qy = q[1], qz = q[2];
  // Mirror reference: d2 = sum(q*q) + sum(p*p) - 2*(q . p)
  float qn = __fadd_rn(__fadd_rn(__fmul_rn(qx, qx), __fmul_rn(qy, qy)),
                       __fmul_rn(qz, qz));

  int cnt = 0;
  int first = 0;
  bool have_first = false;
  for (int chunk = 0; chunk < NPTS / 64 && cnt < NSAMPLE; ++chunk) {
    int p = chunk * 64 + lane;
    float4 r0 = *reinterpret_cast<const float4*>(base + (size_t)p * CH);
    float pn =
        __fadd_rn(__fadd_rn(__fmul_rn(r0.x, r0.x), __fmul_rn(r0.y, r0.y)),
                  __fmul_rn(r0.z, r0.z));
    float dot =
        __fadd_rn(__fadd_rn(__fmul_rn(qx, r0.x), __fmul_rn(qy, r0.y)),
                  __fmul_rn(qz, r0.z));
    float d2 = __fsub_rn(__fadd_rn(qn, pn), __fmul_rn(2.0f, dot));
    bool in_r = d2 < 1.0f;  // RADIUS^2
    unsigned long long mask = __ballot(in_r);
    if (!have_first && mask) {
      first = chunk * 64 + __builtin_ctzll(mask);
      have_first = true;
    }
    int pos = cnt + __popcll(mask & ((1ull << lane) - 1ull));
    if (in_r && pos < NSAMPLE) write_slot(out, base, b, qi, pos, p, r0, qx, qy, qz);
    cnt += __popcll(mask);
  }
  if (cnt < NSAMPLE) {
    // Pad remaining slots with the first in-radius index (reference fill rule).
    int s = cnt + lane;
    if (s < NSAMPLE) {
      float4 r0 = *reinterpret_cast<const float4*>(base + (size_t)first * CH);
      write_slot(out, base, b, qi, s, first, r0, qx, qy, qz);
    }
  }
}

extern "C" void kernel_launch(void* const* d_in, const int* in_sizes, int n_in,
                              void* d_out, int out_size, void* d_ws,
                              size_t ws_size, hipStream_t stream) {
  (void)in_sizes;
  (void)n_in;
  (void)out_size;
  (void)d_ws;
  (void)ws_size;
  const float* in = (const float*)d_in[0];
  float* out = (float*)d_out;
  fps_kernel<<<NB, FPS_THREADS, 0, stream>>>(in, out);
  ballq_kernel<<<(NB * NPOINT) / 4, 256, 0, stream>>>(in, out);
}

// Round 16
// 1842.145 us; speedup vs baseline: 1.2896x; 1.2896x over previous
//
#include <hip/hip_runtime.h>

// File-scope: forbid implicit fma contraction (keeps every a*b+c as two
// single-rounded IEEE ops, matching the numpy reference bit-for-bit).
#pragma clang fp contract(off)

#define NPOINT 2048
#define NSAMPLE 32
#define NPTS 8192
#define NB 4
#define CH 16
#define FPS_THREADS 256
#define PTS_PER_THREAD (NPTS / FPS_THREADS) /* 32 */
#define PAIRS (PTS_PER_THREAD / 2)          /* 16 */
#define FPS_WAVES (FPS_THREADS / 64)        /* 4 */

typedef unsigned long long u64;
typedef float v2f __attribute__((ext_vector_type(2)));

// Output layout (flat float32, concatenated in reference return order)
#define OFF_NEWXYZ 0
#define OFF_NEWPTS (NB * NPOINT * 3)                          /* 24576 */
#define OFF_IDX (OFF_NEWPTS + NB * NPOINT * NSAMPLE * CH)     /* 4218880 */
#define OFF_GXYZ (OFF_IDX + NB * NPOINT * NSAMPLE)            /* 4481024 */

template <int CTRL>
__device__ __forceinline__ float dpp_fmax(float v) {
  // bound_ctrl=true -> 0-fill; distances are >= 0 so 0 is a safe identity.
  int o = __builtin_amdgcn_update_dpp(0, __float_as_int(v), CTRL, 0xf, 0xf, true);
  return fmaxf(v, __int_as_float(o));
}

// ---------------- FPS: one block per batch, sequential 2048-step scan ------
// Reference semantics: idxs[0]=0; each step: dists=min(dists,|p-p_last|^2),
// next = argmax(dists) with FIRST-index tie-break. Op order mirrored:
// (dx*dx + dy*dy) + dz*dz, single-rounded IEEE, no fma contraction.
//
// R14 post-mortem: the winner-lane post-reduce 32-step index scan sat on the
// serial tail (after DPP, before slot write) and cost ~500 cyc/iter. R15:
//  - packed v2f loop WITH in-loop pair tracking (pm>bestv strict -> bestjp,
//    bestpair; 6 inst/pair, hidden under loop ILP);
//  - post-loop index resolve in 3 inst: bestj = 2*bestjp + parity(bestpair);
//  - atomic-free cross-wave exchange (R14): winner lane ds_write_b64's its
//    key; next iter all threads read 4 keys (2 broadcast b128) + 3-compare.
// Tie-breaks (exact jnp.argmax lowest-index): pair parity checks .x first;
// strict '>' keeps lowest jp; ballot-ctz keeps lowest lane; key low word
// (8191-idx) keeps lowest wave. Contiguous ownership keeps (wave,lane,j)
// order == global index order.
__global__ __launch_bounds__(FPS_THREADS)
__attribute__((amdgpu_waves_per_eu(1))) void fps_kernel(
    const float* __restrict__ in, float* __restrict__ out) {
  __shared__ float4 lpxyz[NPTS];      // 128 KB; winner coords: 1 ds_read_b128
  __shared__ float newb[NPOINT * 3];  // 24 KB newxyz staging
  __shared__ alignas(16) u64 slots[2][FPS_WAVES];  // per-wave argmax keys

  const int b = blockIdx.x;
  const int tid = threadIdx.x;
  const int lane = tid & 63;
  const int wv = tid >> 6;
  const float* base = in + (size_t)b * NPTS * CH;

  v2f pxv[PAIRS], pyv[PAIRS], pzv[PAIRS], dv[PAIRS];
#pragma unroll
  for (int jp = 0; jp < PAIRS; ++jp) {
    int p0 = tid * PTS_PER_THREAD + 2 * jp;
    float4 r0 = *reinterpret_cast<const float4*>(base + (size_t)p0 * CH);
    float4 r1 = *reinterpret_cast<const float4*>(base + (size_t)(p0 + 1) * CH);
    pxv[jp] = (v2f){r0.x, r1.x};
    pyv[jp] = (v2f){r0.y, r1.y};
    pzv[jp] = (v2f){r0.z, r1.z};
    lpxyz[p0] = r0;
    lpxyz[p0 + 1] = r1;
    dv[jp] = (v2f){__builtin_inff(), __builtin_inff()};
  }
  // Prime parity-0 slots: slot 0 = (+inf, idx 0) wins the first compare.
  if (tid < FPS_WAVES)
    slots[0][tid] = (tid == 0) ? (((u64)0x7f800000u << 32) | 8191u) : 0ull;

  for (int it = 0; it < NPOINT; ++it) {
    __syncthreads();  // separates slot writes (it-1) from reads (it)
    // Read all 4 wave keys (broadcast, 2x ds_read_b128), 3-compare u64 max.
    const ulonglong2 s01 =
        *reinterpret_cast<const ulonglong2*>(&slots[it & 1][0]);
    const ulonglong2 s23 =
        *reinterpret_cast<const ulonglong2*>(&slots[it & 1][2]);
    u64 k = s01.x;
    k = (s01.y > k) ? s01.y : k;
    k = (s23.x > k) ? s23.x : k;
    k = (s23.y > k) ? s23.y : k;
    const int gi = 8191 - (int)(unsigned)k;  // low 32 bits = 8191-idx
    // Winner coords: broadcast LDS read.
    const float4 g = lpxyz[gi];
    const float gx = g.x, gy = g.y, gz = g.z;
    if (tid == 0) {
      newb[it * 3 + 0] = gx;
      newb[it * 3 + 1] = gy;
      newb[it * 3 + 2] = gz;
    }
    // Distance update (packed pairs; exact IEEE per-element) + in-loop
    // pair-granular argmax tracking (overlaps with loop ILP).
    float bestv = -1.0f;
    int bestjp = 0;
    v2f bestpair = (v2f){-1.0f, -1.0f};
#pragma unroll
    for (int jp = 0; jp < PAIRS; ++jp) {
      v2f dx = pxv[jp] - gx;
      v2f dy = pyv[jp] - gy;
      v2f dz = pzv[jp] - gz;
      v2f nd = (dx * dx + dy * dy) + dz * dz;
      v2f dn = {fminf(dv[jp].x, nd.x), fminf(dv[jp].y, nd.y)};
      dv[jp] = dn;
      float pm = fmaxf(dn.x, dn.y);
      bool t = pm > bestv;  // strict: lowest jp wins ties
      bestjp = t ? jp : bestjp;
      bestpair = t ? dn : bestpair;
      bestv = fmaxf(bestv, pm);
    }
    // Resolve within-pair parity: .x first (lower index) on ties.
    const int bestj = 2 * bestjp + ((bestpair.x == bestv) ? 0 : 1);
    const unsigned besti = (unsigned)(tid * PTS_PER_THREAD + bestj);
    // Wave max via 6 DPP rounds -> lane 63; ballot -> lowest matching lane.
    float wm = bestv;
    wm = dpp_fmax<0x111>(wm);  // row_shr:1
    wm = dpp_fmax<0x112>(wm);  // row_shr:2
    wm = dpp_fmax<0x114>(wm);  // row_shr:4
    wm = dpp_fmax<0x118>(wm);  // row_shr:8
    wm = dpp_fmax<0x142>(wm);  // row_bcast15
    wm = dpp_fmax<0x143>(wm);  // row_bcast31
    const float swm =
        __int_as_float(__builtin_amdgcn_readlane(__float_as_int(wm), 63));
    const u64 wbal = __ballot(bestv == swm);
    const int wl = (int)__builtin_ctzll(wbal);
    if (lane == wl) {  // tiny tail: pack + one ds_write_b64
      slots[(it + 1) & 1][wv] =
          ((u64)__float_as_uint(bestv) << 32) | (8191u - besti);
    }
  }
  __syncthreads();
  // Dump staged newxyz to global once.
  float* ob = out + OFF_NEWXYZ + (size_t)b * NPOINT * 3;
  for (int i = tid; i < NPOINT * 3; i += FPS_THREADS) ob[i] = newb[i];
}

// ---------------- Ball query + group: one wave per query -------------------
__device__ __forceinline__ void write_slot(float* __restrict__ out,
                                           const float* __restrict__ base,
                                           int b, int qi, int s, int p,
                                           float4 r0, float qx, float qy,
                                           float qz) {
  float dx = __fsub_rn(r0.x, qx);
  float dy = __fsub_rn(r0.y, qy);
  float dz = __fsub_rn(r0.z, qz);
  size_t qs = (size_t)b * NPOINT + qi;
  out[OFF_IDX + qs * NSAMPLE + s] = (float)p;  // idx stored as float32
  float* g = out + OFF_GXYZ + (qs * NSAMPLE + s) * 3;
  g[0] = dx;
  g[1] = dy;
  g[2] = dz;
  const float* row = base + (size_t)p * CH;
  float4 r1 = *reinterpret_cast<const float4*>(row + 4);
  float4 r2 = *reinterpret_cast<const float4*>(row + 8);
  float4 r3 = *reinterpret_cast<const float4*>(row + 12);
  float* np_ = out + OFF_NEWPTS + (qs * NSAMPLE + s) * CH;
  *reinterpret_cast<float4*>(np_ + 0) = make_float4(dx, dy, dz, r0.w);
  *reinterpret_cast<float4*>(np_ + 4) = r1;
  *reinterpret_cast<float4*>(np_ + 8) = r2;
  *reinterpret_cast<float4*>(np_ + 12) = r3;
}

__global__ __launch_bounds__(256) void ballq_kernel(
    const float* __restrict__ in, float* __restrict__ out) {
  const int lane = threadIdx.x & 63;
  const int qid = blockIdx.x * 4 + (threadIdx.x >> 6);
  const int b = qid >> 11;    // / NPOINT
  const int qi = qid & 2047;  // % NPOINT
  const float* base = in + (size_t)b * NPTS * CH;
  const float* q = out + OFF_NEWXYZ + ((size_t)b * NPOINT + qi) * 3;
  float qx = q[0], qy = q[1], qz = q[2];
  // Mirror reference: d2 = sum(q*q) + sum(p*p) - 2*(q . p)
  float qn = __fadd_rn(__fadd_rn(__fmul_rn(qx, qx), __fmul_rn(qy, qy)),
                       __fmul_rn(qz, qz));

  int cnt = 0;
  int first = 0;
  bool have_first = false;
  for (int chunk = 0; chunk < NPTS / 64 && cnt < NSAMPLE; ++chunk) {
    int p = chunk * 64 + lane;
    float4 r0 = *reinterpret_cast<const float4*>(base + (size_t)p * CH);
    float pn =
        __fadd_rn(__fadd_rn(__fmul_rn(r0.x, r0.x), __fmul_rn(r0.y, r0.y)),
                  __fmul_rn(r0.z, r0.z));
    float dot =
        __fadd_rn(__fadd_rn(__fmul_rn(qx, r0.x), __fmul_rn(qy, r0.y)),
                  __fmul_rn(qz, r0.z));
    float d2 = __fsub_rn(__fadd_rn(qn, pn), __fmul_rn(2.0f, dot));
    bool in_r = d2 < 1.0f;  // RADIUS^2
    unsigned long long mask = __ballot(in_r);
    if (!have_first && mask) {
      first = chunk * 64 + __builtin_ctzll(mask);
      have_first = true;
    }
    int pos = cnt + __popcll(mask & ((1ull << lane) - 1ull));
    if (in_r && pos < NSAMPLE) write_slot(out, base, b, qi, pos, p, r0, qx, qy, qz);
    cnt += __popcll(mask);
  }
  if (cnt < NSAMPLE) {
    // Pad remaining slots with the first in-radius index (reference fill rule).
    int s = cnt + lane;
    if (s < NSAMPLE) {
      float4 r0 = *reinterpret_cast<const float4*>(base + (size_t)first * CH);
      write_slot(out, base, b, qi, s, first, r0, qx, qy, qz);
    }
  }
}

extern "C" void kernel_launch(void* const* d_in, const int* in_sizes, int n_in,
                              void* d_out, int out_size, void* d_ws,
                              size_t ws_size, hipStream_t stream) {
  (void)in_sizes;
  (void)n_in;
  (void)out_size;
  (void)d_ws;
  (void)ws_size;
  const float* in = (const float*)d_in[0];
  float* out = (float*)d_out;
  fps_kernel<<<NB, FPS_THREADS, 0, stream>>>(in, out);
  ballq_kernel<<<(NB * NPOINT) / 4, 256, 0, stream>>>(in, out);
}

// Round 17
// 1841.693 us; speedup vs baseline: 1.2899x; 1.0002x over previous
//
#include <hip/hip_runtime.h>

// File-scope: forbid implicit fma contraction (keeps every a*b+c as two
// single-rounded IEEE ops, matching the numpy reference bit-for-bit).
#pragma clang fp contract(off)

#define NPOINT 2048
#define NSAMPLE 32
#define NPTS 8192
#define NB 4
#define CH 16
#define FPS_THREADS 512
#define PTS_PER_THREAD (NPTS / FPS_THREADS) /* 16 */
#define PAIRS (PTS_PER_THREAD / 2)          /* 8 */
#define FPS_WAVES (FPS_THREADS / 64)        /* 8 */

typedef unsigned long long u64;
typedef float v2f __attribute__((ext_vector_type(2)));

// Output layout (flat float32, concatenated in reference return order)
#define OFF_NEWXYZ 0
#define OFF_NEWPTS (NB * NPOINT * 3)                          /* 24576 */
#define OFF_IDX (OFF_NEWPTS + NB * NPOINT * NSAMPLE * CH)     /* 4218880 */
#define OFF_GXYZ (OFF_IDX + NB * NPOINT * NSAMPLE)            /* 4481024 */

template <int CTRL>
__device__ __forceinline__ float dpp_fmax(float v) {
  // bound_ctrl=true -> 0-fill; distances are >= 0 so 0 is a safe identity.
  int o = __builtin_amdgcn_update_dpp(0, __float_as_int(v), CTRL, 0xf, 0xf, true);
  return fmaxf(v, __int_as_float(o));
}

// ---------------- FPS: one block per batch, sequential 2048-step scan ------
// Reference semantics: idxs[0]=0; each step: dists=min(dists,|p-p_last|^2),
// next = argmax(dists) with FIRST-index tie-break. Op order mirrored:
// (dx*dx + dy*dy) + dz*dz, single-rounded IEEE, no fma contraction.
//
// Occupancy map so far (waves/SIMD -> fps µs): 4 -> 1910 (issue-bound, 82%
// busy), 1 -> 1803-1865 (latency-exposed, 57% busy), 2 -> 1997 but handicapped
// by an LDS-atomic ring. R17 = the untested corner: 2 waves/SIMD with the
// best structure (atomic-free per-wave slot exchange + packed v2f loop).
// The second wave per SIMD fills the ~43% idle-issue slots that 1-wave
// exposes, at half of 4-wave's issue multiplier.
//  - winner lane ds_write_b64's its key; next iter all threads read 8 keys
//    (4 broadcast b128) + 7-compare u64 max. Parity double-buffer, one
//    barrier/iter.
//  - in-loop tracking: pm>bestv strict -> bestjp + bestx (scalar, 1 cndmask);
//    post-loop parity resolve: bestj = 2*bestjp + (bestx==bestv ? 0 : 1).
// Tie-breaks (exact jnp.argmax lowest-index): parity checks .x first; strict
// '>' keeps lowest jp; ballot-ctz keeps lowest lane; key low word (8191-idx)
// keeps lowest wave. Contiguous ownership (thread t owns t*16..t*16+15)
// keeps (wave,lane,j) order == global index order.
__global__ __launch_bounds__(FPS_THREADS)
__attribute__((amdgpu_waves_per_eu(2))) void fps_kernel(
    const float* __restrict__ in, float* __restrict__ out) {
  __shared__ float4 lpxyz[NPTS];      // 128 KB; winner coords: 1 ds_read_b128
  __shared__ float newb[NPOINT * 3];  // 24 KB newxyz staging
  __shared__ alignas(16) u64 slots[2][FPS_WAVES];  // per-wave argmax keys

  const int b = blockIdx.x;
  const int tid = threadIdx.x;
  const int lane = tid & 63;
  const int wv = tid >> 6;
  const float* base = in + (size_t)b * NPTS * CH;

  v2f pxv[PAIRS], pyv[PAIRS], pzv[PAIRS], dv[PAIRS];
#pragma unroll
  for (int jp = 0; jp < PAIRS; ++jp) {
    int p0 = tid * PTS_PER_THREAD + 2 * jp;
    float4 r0 = *reinterpret_cast<const float4*>(base + (size_t)p0 * CH);
    float4 r1 = *reinterpret_cast<const float4*>(base + (size_t)(p0 + 1) * CH);
    pxv[jp] = (v2f){r0.x, r1.x};
    pyv[jp] = (v2f){r0.y, r1.y};
    pzv[jp] = (v2f){r0.z, r1.z};
    lpxyz[p0] = r0;
    lpxyz[p0 + 1] = r1;
    dv[jp] = (v2f){__builtin_inff(), __builtin_inff()};
  }
  // Prime parity-0 slots: slot 0 = (+inf, idx 0) wins the first compare.
  if (tid < FPS_WAVES)
    slots[0][tid] = (tid == 0) ? (((u64)0x7f800000u << 32) | 8191u) : 0ull;

  for (int it = 0; it < NPOINT; ++it) {
    __syncthreads();  // separates slot writes (it-1) from reads (it)
    // Read all 8 wave keys (broadcast, 4x ds_read_b128), 7-compare u64 max.
    const ulonglong2* sp =
        reinterpret_cast<const ulonglong2*>(&slots[it & 1][0]);
    const ulonglong2 s01 = sp[0];
    const ulonglong2 s23 = sp[1];
    const ulonglong2 s45 = sp[2];
    const ulonglong2 s67 = sp[3];
    u64 ka = (s01.y > s01.x) ? s01.y : s01.x;
    u64 kb = (s23.y > s23.x) ? s23.y : s23.x;
    u64 kc = (s45.y > s45.x) ? s45.y : s45.x;
    u64 kd = (s67.y > s67.x) ? s67.y : s67.x;
    ka = (kb > ka) ? kb : ka;
    kc = (kd > kc) ? kd : kc;
    const u64 k = (kc > ka) ? kc : ka;
    const int gi = 8191 - (int)(unsigned)k;  // low 32 bits = 8191-idx
    // Winner coords: broadcast LDS read.
    const float4 g = lpxyz[gi];
    const float gx = g.x, gy = g.y, gz = g.z;
    if (tid == 0) {
      newb[it * 3 + 0] = gx;
      newb[it * 3 + 1] = gy;
      newb[it * 3 + 2] = gz;
    }
    // Distance update (packed pairs; exact IEEE per-element) + in-loop
    // pair-granular tracking (bestjp + bestx; hidden under loop ILP).
    float bestv = -1.0f;
    float bestx = -1.0f;
    int bestjp = 0;
#pragma unroll
    for (int jp = 0; jp < PAIRS; ++jp) {
      v2f dx = pxv[jp] - gx;
      v2f dy = pyv[jp] - gy;
      v2f dz = pzv[jp] - gz;
      v2f nd = (dx * dx + dy * dy) + dz * dz;
      v2f dn = {fminf(dv[jp].x, nd.x), fminf(dv[jp].y, nd.y)};
      dv[jp] = dn;
      float pm = fmaxf(dn.x, dn.y);
      bool t = pm > bestv;  // strict: lowest jp wins ties
      bestjp = t ? jp : bestjp;
      bestx = t ? dn.x : bestx;
      bestv = fmaxf(bestv, pm);
    }
    // Within-pair parity: .x first (lower index) on ties.
    const int bestj = 2 * bestjp + ((bestx == bestv) ? 0 : 1);
    const unsigned besti = (unsigned)(tid * PTS_PER_THREAD + bestj);
    // Wave max via 6 DPP rounds -> lane 63; ballot -> lowest matching lane.
    float wm = bestv;
    wm = dpp_fmax<0x111>(wm);  // row_shr:1
    wm = dpp_fmax<0x112>(wm);  // row_shr:2
    wm = dpp_fmax<0x114>(wm);  // row_shr:4
    wm = dpp_fmax<0x118>(wm);  // row_shr:8
    wm = dpp_fmax<0x142>(wm);  // row_bcast15
    wm = dpp_fmax<0x143>(wm);  // row_bcast31
    const float swm =
        __int_as_float(__builtin_amdgcn_readlane(__float_as_int(wm), 63));
    const u64 wbal = __ballot(bestv == swm);
    const int wl = (int)__builtin_ctzll(wbal);
    if (lane == wl) {  // tiny tail: pack + one ds_write_b64
      slots[(it + 1) & 1][wv] =
          ((u64)__float_as_uint(bestv) << 32) | (8191u - besti);
    }
  }
  __syncthreads();
  // Dump staged newxyz to global once.
  float* ob = out + OFF_NEWXYZ + (size_t)b * NPOINT * 3;
  for (int i = tid; i < NPOINT * 3; i += FPS_THREADS) ob[i] = newb[i];
}

// ---------------- Ball query + group: one wave per query -------------------
__device__ __forceinline__ void write_slot(float* __restrict__ out,
                                           const float* __restrict__ base,
                                           int b, int qi, int s, int p,
                                           float4 r0, float qx, float qy,
                                           float qz) {
  float dx = __fsub_rn(r0.x, qx);
  float dy = __fsub_rn(r0.y, qy);
  float dz = __fsub_rn(r0.z, qz);
  size_t qs = (size_t)b * NPOINT + qi;
  out[OFF_IDX + qs * NSAMPLE + s] = (float)p;  // idx stored as float32
  float* g = out + OFF_GXYZ + (qs * NSAMPLE + s) * 3;
  g[0] = dx;
  g[1] = dy;
  g[2] = dz;
  const float* row = base + (size_t)p * CH;
  float4 r1 = *reinterpret_cast<const float4*>(row + 4);
  float4 r2 = *reinterpret_cast<const float4*>(row + 8);
  float4 r3 = *reinterpret_cast<const float4*>(row + 12);
  float* np_ = out + OFF_NEWPTS + (qs * NSAMPLE + s) * CH;
  *reinterpret_cast<float4*>(np_ + 0) = make_float4(dx, dy, dz, r0.w);
  *reinterpret_cast<float4*>(np_ + 4) = r1;
  *reinterpret_cast<float4*>(np_ + 8) = r2;
  *reinterpret_cast<float4*>(np_ + 12) = r3;
}

__global__ __launch_bounds__(256) void ballq_kernel(
    const float* __restrict__ in, float* __restrict__ out) {
  const int lane = threadIdx.x & 63;
  const int qid = blockIdx.x * 4 + (threadIdx.x >> 6);
  const int b = qid >> 11;    // / NPOINT
  const int qi = qid & 2047;  // % NPOINT
  const float* base = in + (size_t)b * NPTS * CH;
  const float* q = out + OFF_NEWXYZ + ((size_t)b * NPOINT + qi) * 3;
  float qx = q[0], qy = q[1], qz = q[2];
  // Mirror reference: d2 = sum(q*q) + sum(p*p) - 2*(q . p)
  float qn = __fadd_rn(__fadd_rn(__fmul_rn(qx, qx), __fmul_rn(qy, qy)),
                       __fmul_rn(qz, qz));

  int cnt = 0;
  int first = 0;
  bool have_first = false;
  for (int chunk = 0; chunk < NPTS / 64 && cnt < NSAMPLE; ++chunk) {
    int p = chunk * 64 + lane;
    float4 r0 = *reinterpret_cast<const float4*>(base + (size_t)p * CH);
    float pn =
        __fadd_rn(__fadd_rn(__fmul_rn(r0.x, r0.x), __fmul_rn(r0.y, r0.y)),
                  __fmul_rn(r0.z, r0.z));
    float dot =
        __fadd_rn(__fadd_rn(__fmul_rn(qx, r0.x), __fmul_rn(qy, r0.y)),
                  __fmul_rn(qz, r0.z));
    float d2 = __fsub_rn(__fadd_rn(qn, pn), __fmul_rn(2.0f, dot));
    bool in_r = d2 < 1.0f;  // RADIUS^2
    unsigned long long mask = __ballot(in_r);
    if (!have_first && mask) {
      first = chunk * 64 + __builtin_ctzll(mask);
      have_first = true;
    }
    int pos = cnt + __popcll(mask & ((1ull << lane) - 1ull));
    if (in_r && pos < NSAMPLE) write_slot(out, base, b, qi, pos, p, r0, qx, qy, qz);
    cnt += __popcll(mask);
  }
  if (cnt < NSAMPLE) {
    // Pad remaining slots with the first in-radius index (reference fill rule).
    int s = cnt + lane;
    if (s < NSAMPLE) {
      float4 r0 = *reinterpret_cast<const float4*>(base + (size_t)first * CH);
      write_slot(out, base, b, qi, s, first, r0, qx, qy, qz);
    }
  }
}

extern "C" void kernel_launch(void* const* d_in, const int* in_sizes, int n_in,
                              void* d_out, int out_size, void* d_ws,
                              size_t ws_size, hipStream_t stream) {
  (void)in_sizes;
  (void)n_in;
  (void)out_size;
  (void)d_ws;
  (void)ws_size;
  const float* in = (const float*)d_in[0];
  float* out = (float*)d_out;
  fps_kernel<<<NB, FPS_THREADS, 0, stream>>>(in, out);
  ballq_kernel<<<(NB * NPOINT) / 4, 256, 0, stream>>>(in, out);
}